// Round 8
// baseline (12256.083 us; speedup 1.0000x reference)
//
#include <hip/hip_runtime.h>
#include <hip/hip_bf16.h>
#include <math.h>

typedef unsigned long long u64;
typedef unsigned int u32;

#define T_STEPS 8192
#define HDIM    512
#define NBLK_HW 256          // launched blocks; members are b%8==0 (XCD 0)
#define SPIN_MAX (1 << 20)   // device-path spin bound
#define LSPIN    2048        // local-path spin budget before sticky fallback
#define WARM     8           // device-path warmup steps

#if __has_builtin(__builtin_amdgcn_rcpf)
#define DEV_RCP(x) __builtin_amdgcn_rcpf(x)
#else
#define DEV_RCP(x) (1.0f / (x))
#endif
#if __has_builtin(__builtin_amdgcn_exp2f)
#define DEV_EXP2(x) __builtin_amdgcn_exp2f(x)
#else
#define DEV_EXP2(x) exp2f(x)
#endif

__device__ __forceinline__ float fast_sigmoid(float x) {
    float e = DEV_EXP2(-1.4426950408889634f * x);
    return DEV_RCP(1.0f + e);
}
__device__ __forceinline__ float fast_tanh(float x) {
    x = fminf(20.0f, fmaxf(-20.0f, x));
    float e = DEV_EXP2(-2.8853900817779268f * x);  // e^{-2x}
    return (1.0f - e) * DEV_RCP(1.0f + e);
}

// r19 = r17 (PASS, 11.75ms) + LDS-only barriers. r18's failure analyzed:
// absmax 432 = sentinel 400+b -> sdead fired -> device-path deadlock.
// Root cause: r18 made hpD publishing conditional on the PUBLISHER's own
// per-thread fellback flag, but fallback is per-CONSUMER-thread: a consumer
// of block P's packets can time out while P's publisher lanes (which read
// block 0's elements) never do -> P never stores hpD -> consumer spins to
// SPIN_MAX. r17's UNCONDITIONAL deferred hpD store at S0 is the sound
// design; restored verbatim here.
//
// The one r18 change kept (the actual perf lever): bar_lds = sched_barrier;
// s_waitcnt lgkmcnt(0); s_barrier; sched_barrier (m139 pattern). The
// compiler's __syncthreads emits s_waitcnt vmcnt(0) before s_barrier,
// draining the S0 MALL-store residual + x-prefetch HBM residual at #1
// every step. bar_lds drains only the DS pipe; VMEM flies across barriers.
// Remaining forced drain: each thread's own poll vmcnt(0) in C, covered by
// B (~500cy) except wave0's MALL-store residual (~200cy).
//
// LDS hazard walk under lgkmcnt-only drains (reader's ds_read retires into
// registers at its own lgkmcnt(0) before the barrier; writes are
// post-barrier): x_lds W(D,t) vs R(B,t): reads retired at #1(t), write
// after -> safe; W(D,t) vs R(B,t+1): #2(t). h_lds W(C,t) vs R(D,t): #1(t);
// R(D,t) vs W(C,t+1): #2(t). gate_lds W(D,t) vs R(E,t): #2(t); R(E,t) vs
// W(D,t+1): #1(t+1) (wave0 runs E before reaching #1(t+1)). Prologue keeps
// a full __syncthreads (sdead + x_lds(0) init). Packet WAR: r9-verified
// transitive consume-before-publish argument, unchanged from r17.

__global__ void probe_gate_r19(const float* __restrict__ wih,
                               const float* __restrict__ x, u32* flag) {
    const int lane = threadIdx.x & 63;
    const u32 wi = ((u32)lane * 16381u) & (1048576u - 1u);
    const u32 xi = ((u32)lane * 65521u) % 4194304u;
    const float wv = wih[wi];
    const float xv = x[xi];
    const bool wok  = (fabsf(wv) <= 0.04425f);            // NaN -> false
    const bool xbig = (fabsf(xv) > 0.5f) && (fabsf(xv) < 100.0f);
    const u64 wm = __ballot(wok);
    const u64 xm = __ballot(xbig);
    if (lane == 0) {
        u32 f = 1u;
        if (__popcll(wm) < 64) f = 2u;
        else if (__popcll(xm) < 8) f = 3u;
        __hip_atomic_store(flag, f, __ATOMIC_RELAXED, __HIP_MEMORY_SCOPE_AGENT);
    }
}

__global__ void diag_sizes_r19(float v, float* out) {
    const int tid = threadIdx.x;  // 512 threads
    out[tid] = (tid == 0) ? v : 0.0f;
}

// sc0 load: bypass L1, served by the (XCD-shared) L2. 8B single transaction.
__device__ __forceinline__ u64 load_b64_sc0(const u64* p) {
    u64 r;
    asm volatile("global_load_dwordx2 %0, %1, off sc0\n\t"
                 "s_waitcnt vmcnt(0)"
                 : "=v"(r) : "v"(p) : "memory");
    return r;
}
// plain store: lands in this XCD's L2.
__device__ __forceinline__ void store_b64_l2(u64* p, u64 v) {
    asm volatile("global_store_dwordx2 %0, %1, off"
                 :: "v"(p), "v"(v) : "memory");
}

// LDS-only barrier: drains DS ops, leaves VMEM in flight (no vmcnt drain).
__device__ __forceinline__ void bar_lds() {
    __builtin_amdgcn_sched_barrier(0);
    asm volatile("s_waitcnt lgkmcnt(0)" ::: "memory");
    __builtin_amdgcn_s_barrier();
    __builtin_amdgcn_sched_barrier(0);
}

// ---------------------------------------------------------------------------
// Fused persistent LSTM (r17 structure + vmcnt-free barriers). 256 blocks x
// 512 threads; members b%8==0 (32, one XCD). Member b owns h[16b..16b+16).
// Wave w: gate g=w>>1 (i,f,g,o), row-half rh=w&1. Lane: rl=rh*8+(lane&7);
// p=lane>>3 -> k-part (8 x 64-wide). Per lane: Wh[64]+Wx[64] in VGPRs.
// Chunk rotation ch=(c+p)&15 -> conflict-free LDS broadcasts.
// step = S0 deferred-hpD-store + prefetch issue | B x-dot | C consume ->
// h_lds | #1(lds) | D h-dot + reduce + act -> gate_lds, stage x_lds(t+1) |
// #2(lds) | E update + hpL publish (+hpD iff warm).
// ---------------------------------------------------------------------------
__global__ __launch_bounds__(512, 1) void lstm_rec_r19(
        const float* __restrict__ x, const float* __restrict__ likes,
        const float* __restrict__ wih, const float* __restrict__ whh,
        const float* __restrict__ bih, const float* __restrict__ bhh,
        const u32* __restrict__ dflag, u64* hp, float* __restrict__ out) {
    const int tid = threadIdx.x;
    const int bhw = blockIdx.x;
    if (bhw & 7) return;            // non-members exit (other XCDs)
    const int b = bhw >> 3;

    const u32 f = __hip_atomic_load(dflag, __ATOMIC_RELAXED,
                                    __HIP_MEMORY_SCOPE_AGENT);
    if (f != 1u) {
        if (b == 0 && tid == 0) out[0] = (f == 2u) ? 9000.0f : 9500.0f;
        return;
    }

    const int w    = tid >> 6;
    const int lane = tid & 63;
    const int g    = w >> 1;
    const int rl   = ((w & 1) << 3) + (lane & 7);
    const int p    = lane >> 3;
    const int row  = g * 512 + b * 16 + rl;

    __shared__ __align__(16) float x_lds[HDIM];
    __shared__ __align__(16) float h_lds[HDIM];
    __shared__ float gate_lds[64];      // ACTIVATED gates: i,f,g,o x 16
    __shared__ int   sdead;

    u64* hpD = hp;                  // device-coherent packet dbuf (MALL path)
    u64* hpL = hp + 2 * HDIM;       // XCD-L2 packet dbuf (fast path)

    // W fragments: 64-wide k-slice, rotated chunks ch=(c+p)&15.
    float Wh[64], Wx[64];
    {
        const float* wrh = whh + (size_t)row * 512 + (p << 6);
        const float* wrx = wih + (size_t)row * 512 + (p << 6);
#pragma unroll
        for (int c = 0; c < 16; ++c) {
            const int ch = (c + p) & 15;
            const float4 h4v = *(const float4*)(wrh + (ch << 2));
            const float4 x4v = *(const float4*)(wrx + (ch << 2));
            Wh[4 * c + 0] = h4v.x; Wh[4 * c + 1] = h4v.y;
            Wh[4 * c + 2] = h4v.z; Wh[4 * c + 3] = h4v.w;
            Wx[4 * c + 0] = x4v.x; Wx[4 * c + 1] = x4v.y;
            Wx[4 * c + 2] = x4v.z; Wx[4 * c + 3] = x4v.w;
        }
    }
    const float bsum = bih[row] + bhh[row];

    // prologue: stage x[0]; lk for t=0; zero sdead.
    float lkc = 0.0f, lkn = 0.0f;
    if (tid < 16) lkc = likes[b * 16 + tid];
    if (tid == 0) sdead = 0;
    x_lds[tid] = x[tid];
    __syncthreads();   // prologue barrier (full): x_lds(0) + sdead visible

    float xr     = 0.0f;   // x[t+1][tid], issued at S0(t)
    float creg   = 0.0f;
    u64   pktreg = 0;      // publisher lanes: pkt(tag t+1), made at E(t)
    int   dead   = 0;
    int   fellback = 0;    // sticky: local path timed out -> device path

    for (int t = 0; t < T_STEPS; ++t) {
        // ---- S0: deferred UNCONDITIONAL MALL publish + prefetch issue.
        // No barrier above; retires covered by B+C before any forced drain.
        if (tid < 16 && t > WARM + 1) {
            // pkt(tag t) was NOT stored to hpD in E(t-1) -> store it now.
            __hip_atomic_store(hpD + (size_t)(t & 1) * HDIM + b * 16 + tid,
                               pktreg, __ATOMIC_RELAXED,
                               __HIP_MEMORY_SCOPE_AGENT);
        }
        if (t + 1 < T_STEPS) {
            xr = x[(size_t)(t + 1) * HDIM + tid];
            if (tid < 16)
                lkn = (t + 1 < T_STEPS - 1)
                    ? likes[(size_t)(t + 1) * HDIM + b * 16 + tid] : 0.0f;
        }

        // ---- B: x-part of the dot (reads x_lds staged last step).
        float acc = 0.0f;
        {
            const float4* x4 = (const float4*)x_lds;
#pragma unroll
            for (int c = 0; c < 16; ++c) {
                const int ch = (c + p) & 15;
                const float4 xw = x4[(p << 4) + ch];
                acc = fmaf(Wx[4 * c + 0], xw.x, acc);
                acc = fmaf(Wx[4 * c + 1], xw.y, acc);
                acc = fmaf(Wx[4 * c + 2], xw.z, acc);
                acc = fmaf(Wx[4 * c + 3], xw.w, acc);
            }
        }

        // ---- C: obtain h_t and stage it (r12-verified protocol).
        if (t == 0) {
            h_lds[tid] = 0.0f;
        } else {
            const u32 tag = (u32)t;
            const u64* hsD = hpD + (size_t)(t & 1) * HDIM + tid;
            const u64* hsL = hpL + (size_t)(t & 1) * HDIM + tid;
            u64 v = 0;
            bool got = false;
            if (t > WARM && !fellback) {
                int sp = 0;
                do {
                    v = load_b64_sc0(hsL);
                } while ((u32)(v >> 32) != tag && ++sp < LSPIN);
                if ((u32)(v >> 32) == tag) got = true;
                else fellback = 1;              // sticky; never retry local
            }
            if (!got) {
                v = __hip_atomic_load(hsD, __ATOMIC_RELAXED,
                                      __HIP_MEMORY_SCOPE_AGENT);
                int sp = 0;
                while (!dead && (u32)(v >> 32) != tag) {
                    if (++sp >= SPIN_MAX) { dead = 1; sdead = 1; break; }
                    v = __hip_atomic_load(hsD, __ATOMIC_RELAXED,
                                          __HIP_MEMORY_SCOPE_AGENT);
                }
            }
            h_lds[tid] = __uint_as_float((u32)v);
        }
        bar_lds();   // #1: h_lds ready (DS drain only; VMEM stays in flight)

        // ---- D: h-dot + reduce + ACTIVATION; stage x_lds for t+1.
        {
            const float4* h4 = (const float4*)h_lds;
#pragma unroll
            for (int c = 0; c < 16; ++c) {
                const int ch = (c + p) & 15;
                const float4 hv = h4[(p << 4) + ch];
                acc = fmaf(Wh[4 * c + 0], hv.x, acc);
                acc = fmaf(Wh[4 * c + 1], hv.y, acc);
                acc = fmaf(Wh[4 * c + 2], hv.z, acc);
                acc = fmaf(Wh[4 * c + 3], hv.w, acc);
            }
        }
        x_lds[tid] = xr;          // stage x[t+1] (B-reads retired at #1)
        acc += __shfl_xor(acc, 8);
        acc += __shfl_xor(acc, 16);
        acc += __shfl_xor(acc, 32);
        if (p == 0) {  // lanes 0..7 of each wave
            const float z = acc + bsum;
            gate_lds[g * 16 + rl] = (g == 2) ? fast_tanh(z) : fast_sigmoid(z);
        }
        bar_lds();   // #2: gates + x_lds(t+1) visible (DS drain only)

        // ---- E: cell/h update + fast publish (wave 0 lanes 0..15).
        if (tid < 16) {
            const float gi = gate_lds[tid];
            const float gf = gate_lds[16 + tid];
            const float gg = gate_lds[32 + tid];
            const float go = gate_lds[48 + tid];
            const float cn = fmaf(gf, creg, gi * gg);
            creg = cn;
            const float hn = fmaf(go, fast_tanh(cn), lkc);
            const u64 pkt = ((u64)(u32)(t + 1) << 32) | (u64)__float_as_uint(hn);
            const size_t off = (size_t)((t + 1) & 1) * HDIM + b * 16 + tid;
            store_b64_l2(hpL + off, pkt);           // XCD L2 copy (fast path)
            if (t + 1 <= WARM + 1) {
                // warm steps: device path is primary -> store hpD NOW.
                __hip_atomic_store(hpD + off, pkt, __ATOMIC_RELAXED,
                                   __HIP_MEMORY_SCOPE_AGENT);
            }
            pktreg = pkt;                           // else deferred to S0(t+1)
            if (t == T_STEPS - 1)
                out[b * 16 + tid] = sdead ? (float)(400 + b) : hn;
            lkc = lkn;
        }
        // Non-publisher waves proceed straight to S0/B of t+1.
    }
}

// ---------------------------------------------------------------------------
extern "C" void kernel_launch(void* const* d_in, const int* in_sizes, int n_in,
                              void* d_out, int out_size, void* d_ws, size_t ws_size,
                              hipStream_t stream) {
    float* out = (float*)d_out;
    u64* hp    = (u64*)d_ws;                          // 16 KB dual packet dbuf
    u32* probe = (u32*)((char*)d_ws + 16384);         // probe gate flag

    const int SX = 4194304, SL = 4193792, SW = 1048576, SB = 2048;

    auto match6 = [&](int a0, int a1, int a2, int a3, int a4, int a5) {
        return n_in == 6 && in_sizes[0] == a0 && in_sizes[1] == a1 &&
               in_sizes[2] == a2 && in_sizes[3] == a3 && in_sizes[4] == a4 &&
               in_sizes[5] == a5;
    };

    // Mapping verified by r9 PASS: dict order.
    int ix, il, iwih, iwhh, ibi, ibh;
    if (match6(SX, SL, SW, SW, SB, SB)) {
        ix = 0; il = 1; iwih = 2; iwhh = 3; ibi = 4; ibh = 5;
    } else if (match6(SB, SB, SL, SW, SW, SX)) {
        ibh = 0; ibi = 1; il = 2; iwhh = 3; iwih = 4; ix = 5;
    } else if (match6(SB, SB, SW, SW, SL, SX)) {
        ibh = 0; ibi = 1; iwhh = 2; iwih = 3; il = 4; ix = 5;
    } else {
        const float v = 4.0e6f + (float)(n_in == 6 ? in_sizes[0] : 100000 * n_in);
        hipLaunchKernelGGL(diag_sizes_r19, dim3(1), dim3(512), 0, stream, v, out);
        return;
    }

    const float* x   = (const float*)d_in[ix];
    const float* lk  = (const float*)d_in[il];
    const float* wih = (const float*)d_in[iwih];
    const float* whh = (const float*)d_in[iwhh];
    const float* bih = (const float*)d_in[ibi];
    const float* bhh = (const float*)d_in[ibh];

    // Zero packets + probe each launch (capture-legal).
    hipMemsetAsync(d_ws, 0, 32768, stream);

    hipLaunchKernelGGL(probe_gate_r19, dim3(1), dim3(64), 0, stream, wih, x, probe);
    hipLaunchKernelGGL(lstm_rec_r19, dim3(NBLK_HW), dim3(512), 0, stream,
                       x, lk, wih, whh, bih, bhh, (const u32*)probe, hp, out);
}